// Round 6
// baseline (125.208 us; speedup 1.0000x reference)
//
#include <hip/hip_runtime.h>
#include <hip/hip_fp16.h>
#include <math.h>

#define H_IN   256
#define W_IN   256
#define CIN    3
#define COUT   128
#define NB     8
#define H_OUT  254
#define W_OUT  254
#define ROW_F  (W_IN * CIN)       // 768 floats per input row
#define XH_SZ  3328               // 3*768 staged + zeroed slack (covers k>=27 reads)

typedef _Float16 half4 __attribute__((ext_vector_type(4)));
typedef float    f32x4 __attribute__((ext_vector_type(4)));

__global__ __launch_bounds__(256, 4)
void conv_mfma_kernel(const float* __restrict__ in,
                      const float* __restrict__ w_mu,
                      const float* __restrict__ w_sigma,
                      float* __restrict__ out)
{
    __shared__ _Float16 xh[XH_SZ];

    const int h    = blockIdx.x;       // 0..253
    const int n    = blockIdx.y;       // 0..7
    const int tid  = threadIdx.x;      // 0..255
    const int lane = tid & 63;
    const int wid  = tid >> 6;         // wave 0..3
    const int g    = lane >> 4;        // 0..3
    const int m    = lane & 15;        // 0..15

    // ---- B fragments for the 8 channel-tiles: B[k][n], n = t*16+m,
    //      k = g*4+j+16*hf, zero-padded for k>=27. (classic 16x16x16f16 layout)
    half4 bw[8][2];
    #pragma unroll
    for (int t = 0; t < 8; ++t) {
        #pragma unroll
        for (int hf = 0; hf < 2; ++hf) {
            #pragma unroll
            for (int j = 0; j < 4; ++j) {
                const int k = g * 4 + j + 16 * hf;
                const float w = (k < 27) ? w_mu[k * COUT + t * 16 + m] : 0.f;
                bw[t][hf][j] = (_Float16)w;
            }
        }
    }

    // ones-column B for the sum-of-squares MFMA (column n=0 only)
    half4 bones;
    #pragma unroll
    for (int j = 0; j < 4; ++j) bones[j] = (m == 0) ? (_Float16)1.f : (_Float16)0.f;

    // softplus(w_sigma) for my 8 channels (t*16 + m)
    float sp[8];
    #pragma unroll
    for (int t = 0; t < 8; ++t) sp[t] = log1pf(expf(w_sigma[t * 16 + m]));

    // A-gather LDS element offsets for my 8 (g,j) K-slots: k -> (kh,kw,ci)
    int offE[8];
    #pragma unroll
    for (int jh = 0; jh < 8; ++jh) {
        const int k  = g * 4 + (jh & 3) + 16 * (jh >> 2);
        const int kh = k / 9, r9 = k - kh * 9;
        const int kw = r9 / 3, ci = r9 - kw * 3;
        offE[jh] = kh * ROW_F + kw * CIN + ci;   // k>=27 -> kh=3 -> zeroed slack
    }

    // ---- stage 3 input rows as f16; zero the slack region ----
    const float* src = in + (size_t)(n * H_IN + h) * ROW_F;
    for (int i = tid; i < XH_SZ; i += 256)
        xh[i] = (i < 3 * ROW_F) ? (_Float16)src[i] : (_Float16)0.f;
    __syncthreads();

    const size_t pix_base = (size_t)(n * H_OUT + h) * W_OUT;
    float* const out_sig  = out + (size_t)NB * H_OUT * W_OUT * COUT;

    #pragma unroll 1
    for (int pass = 0; pass < 4; ++pass) {
        const int pbase = pass * 64 + wid * 16;  // this wave's 16-pixel base
        const int p3    = (pbase + m) * 3;       // my A-row pixel, in elements

        // A fragments: A[m][k] = x(pixel pbase+m, k); k>=27 reads zeros
        half4 alo, ahi;
        #pragma unroll
        for (int j = 0; j < 4; ++j) alo[j] = xh[offE[j] + p3];
        #pragma unroll
        for (int j = 0; j < 4; ++j) ahi[j] = xh[offE[4 + j] + p3];

        const half4 alo2 = alo * alo;            // v_pk_mul_f16
        const half4 ahi2 = ahi * ahi;

        const f32x4 z = {0.f, 0.f, 0.f, 0.f};
        f32x4 acc[8];
        #pragma unroll
        for (int t = 0; t < 8; ++t) acc[t] = z;
        f32x4 ssa = z;

        #pragma unroll
        for (int t = 0; t < 8; ++t) {
            acc[t] = __builtin_amdgcn_mfma_f32_16x16x16f16(alo, bw[t][0], acc[t], 0, 0, 0);
            acc[t] = __builtin_amdgcn_mfma_f32_16x16x16f16(ahi, bw[t][1], acc[t], 0, 0, 0);
        }
        ssa = __builtin_amdgcn_mfma_f32_16x16x16f16(alo2, bones, ssa, 0, 0, 0);
        ssa = __builtin_amdgcn_mfma_f32_16x16x16f16(ahi2, bones, ssa, 0, 0, 0);

        // ---- stores: pixel q = pbase + g*4 + r, channel t*16 + m ----
        float* const bmu = out     + (pix_base + pbase) * COUT;
        float* const bsg = out_sig + (pix_base + pbase) * COUT;
        const int vo = g * 4 * COUT + m;         // lane element offset

        #pragma unroll
        for (int r = 0; r < 4; ++r) {
            const int q = pbase + g * 4 + r;
            // broadcast sumsq of pixel q from the group leader (lane m==0)
            const float ssr = __shfl(ssa[r], lane & 48, 64);
            if (q < W_OUT) {
                #pragma unroll
                for (int t = 0; t < 8; ++t) {
                    bmu[vo + r * COUT + t * 16] = acc[t][r];
                    bsg[vo + r * COUT + t * 16] = ssr * sp[t];
                }
            }
        }
    }
}

extern "C" void kernel_launch(void* const* d_in, const int* in_sizes, int n_in,
                              void* d_out, int out_size, void* d_ws, size_t ws_size,
                              hipStream_t stream)
{
    const float* in      = (const float*)d_in[0];
    const float* w_mu    = (const float*)d_in[1];
    const float* w_sigma = (const float*)d_in[2];
    float* out           = (float*)d_out;

    dim3 grid(H_OUT, NB);   // one output row per block (known-good dispatch shape)
    dim3 block(256);
    conv_mfma_kernel<<<grid, block, 0, stream>>>(in, w_mu, w_sigma, out);
}

// Round 7
// 115.713 us; speedup vs baseline: 1.0821x; 1.0821x over previous
//
#include <hip/hip_runtime.h>
#include <hip/hip_fp16.h>
#include <math.h>

// Problem constants
#define H_IN   256
#define W_IN   256
#define CIN    3
#define COUT   128
#define NB     8
#define KS     3
#define H_OUT  254
#define W_OUT  254
#define ROW_F  (W_IN * CIN)          // 768 floats per input row

typedef float f32x4 __attribute__((ext_vector_type(4)));

// v_fma_mix_f32: acc(f32) += f16(half of wpk) * x(f32)
#define FMA_MIX_LO(acc, wp, xv) \
    asm("v_fma_mix_f32 %0, %1, %2, %0 op_sel:[0,0,0] op_sel_hi:[1,0,0]" \
        : "+v"(acc) : "v"(wp), "v"(xv))
#define FMA_MIX_HI(acc, wp, xv) \
    asm("v_fma_mix_f32 %0, %1, %2, %0 op_sel:[1,0,0] op_sel_hi:[1,0,0]" \
        : "+v"(acc) : "v"(wp), "v"(xv))

__global__ __launch_bounds__(256, 4)
void conv_meanvar_kernel(const float* __restrict__ in,
                         const float* __restrict__ w_mu,
                         const float* __restrict__ w_sigma,
                         float* __restrict__ out)
{
    __shared__ float lds[3 * ROW_F + 32];

    // ---- XCD-aware swizzle (T1): dispatch slot s -> XCD s&7 (round-robin).
    // Give XCD k batch image n=k and walk h sequentially: each XCD writes one
    // contiguous 33MB mu slab + one 33MB sigma slab instead of 1MB-stride hops.
    const int s   = blockIdx.x;        // 0..2031
    const int n   = s & 7;             // batch image == XCD slot
    const int h   = s >> 3;            // 0..253, sequential per XCD
    const int tid = threadIdx.x;       // 0..255
    const int px  = tid >> 5;          // pixel-group slot 0..7 (4 pixels each)
    const int c4  = (tid & 31) * 4;    // channel quad base 0..124

    // ---- stage rows h..h+2 (2304 floats) via aligned float4 ----
    const float* src = in + (size_t)(n * H_IN + h) * ROW_F;   // 16B-aligned
    if (tid < 144) {
        const f32x4* s4 = reinterpret_cast<const f32x4*>(src) + tid * 4;
        f32x4* d4 = reinterpret_cast<f32x4*>(lds) + tid * 4;
        d4[0] = s4[0]; d4[1] = s4[1]; d4[2] = s4[2]; d4[3] = s4[3];
    }

    // ---- weights for my 4 channels -> 27 packed-f16 pairs (54 VGPRs) ----
    unsigned int wpk[27][2];
    #pragma unroll
    for (int kk = 0; kk < 27; ++kk) {
        f32x4 w = *reinterpret_cast<const f32x4*>(w_mu + kk * COUT + c4);
        wpk[kk][0] = (unsigned int)__half_as_ushort(__float2half(w.x))
                   | ((unsigned int)__half_as_ushort(__float2half(w.y)) << 16);
        wpk[kk][1] = (unsigned int)__half_as_ushort(__float2half(w.z))
                   | ((unsigned int)__half_as_ushort(__float2half(w.w)) << 16);
    }

    // ---- softplus(w_sigma) for my 4 channels (fp32) ----
    f32x4 ws = *reinterpret_cast<const f32x4*>(w_sigma + c4);
    float sp[4];
    sp[0] = log1pf(expf(ws.x));
    sp[1] = log1pf(expf(ws.y));
    sp[2] = log1pf(expf(ws.z));
    sp[3] = log1pf(expf(ws.w));

    __syncthreads();

    const size_t pix_base = (size_t)(n * H_OUT + h) * W_OUT;
    float* const out_sig  = out + (size_t)NB * H_OUT * W_OUT * COUT;

    #pragma unroll 1
    for (int it = 0; it < 8; ++it) {
        const int p0 = it * 32 + px * 4;      // first of my 4 pixels (mult of 4)

        float mu[4][4];
        float ss[4];
        #pragma unroll
        for (int j = 0; j < 4; ++j) {
            ss[j] = 0.f;
            mu[j][0] = mu[j][1] = mu[j][2] = mu[j][3] = 0.f;
        }

        #pragma unroll
        for (int kh = 0; kh < KS; ++kh) {
            const f32x4* rq = reinterpret_cast<const f32x4*>(
                                  &lds[kh * ROW_F + p0 * 3]);
            float r[20];
            *reinterpret_cast<f32x4*>(&r[0])  = rq[0];
            *reinterpret_cast<f32x4*>(&r[4])  = rq[1];
            *reinterpret_cast<f32x4*>(&r[8])  = rq[2];
            *reinterpret_cast<f32x4*>(&r[12]) = rq[3];
            *reinterpret_cast<f32x4*>(&r[16]) = rq[4];

            #pragma unroll
            for (int j = 0; j < 4; ++j) {
                #pragma unroll
                for (int q = 0; q < 9; ++q) {
                    const float x = r[j * 3 + q];
                    const int kk = kh * 9 + q;
                    FMA_MIX_LO(mu[j][0], wpk[kk][0], x);
                    FMA_MIX_HI(mu[j][1], wpk[kk][0], x);
                    FMA_MIX_LO(mu[j][2], wpk[kk][1], x);
                    FMA_MIX_HI(mu[j][3], wpk[kk][1], x);
                    ss[j] = fmaf(x, x, ss[j]);
                }
            }
        }

        #pragma unroll
        for (int j = 0; j < 4; ++j) {
            const int p = p0 + j;
            if (p < W_OUT) {
                const size_t o = (pix_base + p) * COUT + c4;
                f32x4 m = {mu[j][0], mu[j][1], mu[j][2], mu[j][3]};
                *reinterpret_cast<f32x4*>(out + o) = m;
                f32x4 sg = {ss[j] * sp[0], ss[j] * sp[1],
                            ss[j] * sp[2], ss[j] * sp[3]};
                *reinterpret_cast<f32x4*>(out_sig + o) = sg;
            }
        }
    }
}

extern "C" void kernel_launch(void* const* d_in, const int* in_sizes, int n_in,
                              void* d_out, int out_size, void* d_ws, size_t ws_size,
                              hipStream_t stream)
{
    const float* in      = (const float*)d_in[0];
    const float* w_mu    = (const float*)d_in[1];
    const float* w_sigma = (const float*)d_in[2];
    float* out           = (float*)d_out;

    dim3 grid(H_OUT * NB);   // 2032 blocks, 1-D for XCD swizzle
    dim3 block(256);
    conv_meanvar_kernel<<<grid, block, 0, stream>>>(in, w_mu, w_sigma, out);
}